// Round 15
// baseline (176.941 us; speedup 1.0000x reference)
//
#include <hip/hip_runtime.h>
#include <hip/hip_fp16.h>

#define N_NODES 50000
#define N_EDGES 800000
#define IN_DIM  64
#define OUT_DIM 32
#define NODES_PER_BIN 32
#define NBINS   1563                 // ceil(50000/32)
#define NCLS    8
#define CLS_CAP 128                  // per (bin,class): mean 64, +8 sigma; chaining backstops
#define BIN_SLOTS (NCLS * CLS_CAP)   // 1024
#define NCURS   (NBINS * NCLS)       // 12504
#define SCATTER_BLOCKS (N_EDGES / 256)            // 3125 (1 edge/thread)
#define FC_NODES_PER_BLOCK 16
#define FC_BLOCKS (N_NODES / FC_NODES_PER_BLOCK)  // 3125

typedef float f32x4 __attribute__((ext_vector_type(4)));  // nt-load-compatible

// physical XCD id (gfx950: HW_REG_XCC_ID = hwreg 20; learn_hip m09)
__device__ __forceinline__ int get_xcc_id() {
  return (int)(__builtin_amdgcn_s_getreg(63508) & 7u);  // 20 | (31<<11)
}

// Fused K1: scatter blocks (1 edge/thread, XCC-id class + chaining) then fc
// blocks (16 nodes/block). Payload store NORMAL (R13's nt store doubled write
// traffic); read-once streams (src/dst/weight/h) use NON-TEMPORAL LOADS so
// they don't evict the payload write-frontier lines from L2.
// ezh2[n*32+o] = {exp(z[n,b0,o]), exp(z[n,b1,o])};  a_tab[n]=(as0,ad0,as1,ad1)
__global__ __launch_bounds__(256) void fused_fc_scatter_kernel(
    const float* __restrict__ h, const float* __restrict__ Wfc,
    const float* __restrict__ bfc, const float* __restrict__ Watt,
    const int* __restrict__ src, const int* __restrict__ dst,
    const float* __restrict__ weight,
    __half2* __restrict__ ezh2, float4* __restrict__ a_tab,
    int* __restrict__ cursor, unsigned int* __restrict__ payload) {
  __shared__ float Wl[IN_DIM * OUT_DIM];                    // 8 KB
  __shared__ float4 hs4[FC_NODES_PER_BLOCK * 2 * 16];       // 8 KB
  int t = threadIdx.x;

  if (blockIdx.x < SCATTER_BLOCKS) {
    int xcc = get_xcc_id();                  // wave-uniform
    int e = blockIdx.x * 256 + t;            // exact coverage
    int s = __builtin_nontemporal_load(&src[e]);
    int d = __builtin_nontemporal_load(&dst[e]);
    float wv = __builtin_nontemporal_load(&weight[e]);
    unsigned int rec = ((unsigned int)s << 16) | ((unsigned int)(d & 31) << 11) |
                       ((unsigned int)__float2int_rn(wv * 2047.0f) & 2047u);
    int bin = d >> 5;
    int c = xcc;
#pragma unroll
    for (int a = 0; a < NCLS; ++a) {
      int pos = atomicAdd(&cursor[bin * NCLS + c], 1);
      if (pos < CLS_CAP) {
        payload[(size_t)bin * BIN_SLOTS + c * CLS_CAP + pos] = rec;
        break;
      }
      c = (c + 1) & 7;                       // overflow chain: ~never taken
    }
    return;
  }

  // ---- fc role: 16 nodes per block ----
  int n0 = (blockIdx.x - SCATTER_BLOCKS) * FC_NODES_PER_BLOCK;
  for (int i = t; i < 512; i += 256)
    ((float4*)Wl)[i] = ((const float4*)Wfc)[i];
#pragma unroll
  for (int f = t; f < FC_NODES_PER_BLOCK * 2 * 16; f += 256) {
    int ns = f >> 5, sb = (f >> 4) & 1, i4 = f & 15;
    f32x4 v = __builtin_nontemporal_load(
        &((const f32x4*)h)[((size_t)sb * N_NODES + (n0 + ns)) * 16 + i4]);
    hs4[f] = make_float4(v.x, v.y, v.z, v.w);
  }
  __syncthreads();
  int w = t >> 6, lane = t & 63, o = lane & 31, b = lane >> 5;
  float wreg[IN_DIM];
#pragma unroll
  for (int i = 0; i < IN_DIM; ++i) wreg[i] = Wl[i * OUT_DIM + o];
  float bo = bfc[o];
  float wo1 = Watt[o], wo2 = Watt[OUT_DIM + o];
#pragma unroll
  for (int k = 0; k < 4; ++k) {
    int ns = w * 4 + k;
    int n = n0 + ns;
    float acc = bo;
#pragma unroll
    for (int i4 = 0; i4 < 16; ++i4) {
      float4 hv = hs4[(ns * 2 + b) * 16 + i4];   // wave-broadcast (2 addrs: free)
      acc = fmaf(hv.x, wreg[i4 * 4 + 0], acc);
      acc = fmaf(hv.y, wreg[i4 * 4 + 1], acc);
      acc = fmaf(hv.z, wreg[i4 * 4 + 2], acc);
      acc = fmaf(hv.w, wreg[i4 * 4 + 3], acc);
    }
    float ez = __expf(acc);
    float ezo = __shfl(ez, lane ^ 32, 64);       // partner batch's value
    if (b == 0) {
      __half2 hv2;
      hv2.x = __float2half(ez);
      hv2.y = __float2half(ezo);
      ezh2[(size_t)n * OUT_DIM + o] = hv2;
    }
    float ps = acc * wo1, pd = acc * wo2;
#pragma unroll
    for (int m = 16; m >= 1; m >>= 1) {
      ps += __shfl_xor(ps, m, 64);
      pd += __shfl_xor(pd, m, 64);
    }
    if (o == 0) ((float2*)(a_tab + n))[b] = make_float2(ps, pd);
  }
}

// K2 (R13's version): 2 blocks per bin; LDS counting sort (int atomics),
// each wave owns 4 nodes; half-wave (rr) record split; half2 ez gathers.
__global__ __launch_bounds__(256) void accum_kernel(
    const __half2* __restrict__ ezh2, const unsigned int* __restrict__ payload,
    const int* __restrict__ cursor, const float4* __restrict__ a_tab4,
    const float* __restrict__ Watt, const float* __restrict__ batt,
    float* __restrict__ out) {
  __shared__ unsigned int rec[BIN_SLOTS];     // 4 KB
  __shared__ unsigned int sorted[BIN_SLOTS];  // 4 KB
  __shared__ int c8[NCLS];
  __shared__ int hist[NODES_PER_BIN];
  __shared__ int off[NODES_PER_BIN];
  __shared__ int cnt2[NODES_PER_BIN];
  int t = threadIdx.x;
  int bin = blockIdx.x >> 1;
  int half = blockIdx.x & 1;
  if (t < NCLS) {
    int c = cursor[bin * NCLS + t];
    c8[t] = c > CLS_CAP ? CLS_CAP : (c < 0 ? 0 : c);
  }
  if (t < NODES_PER_BIN) { hist[t] = 0; cnt2[t] = 0; }
  __syncthreads();
  const unsigned int* seg = payload + (size_t)bin * BIN_SLOTS;
  for (int j = t; j < BIN_SLOTS; j += 256) {
    unsigned int r = seg[j];
    rec[j] = r;
    if ((j & (CLS_CAP - 1)) < c8[j >> 7]) atomicAdd(&hist[(r >> 11) & 31], 1);
  }
  __syncthreads();
  if (t < 64) {  // exclusive shuffle scan of 32 counts (wave 0)
    int v = (t < 32) ? hist[t] : 0;
    int orig = v;
#pragma unroll
    for (int d1 = 1; d1 < 32; d1 <<= 1) {
      int x = __shfl_up(v, d1, 64);
      if (t >= d1) v += x;
    }
    if (t < 32) off[t] = v - orig;
  }
  __syncthreads();
  for (int j = t; j < BIN_SLOTS; j += 256) {
    if ((j & (CLS_CAP - 1)) < c8[j >> 7]) {
      unsigned int r = rec[j];
      int nl = (r >> 11) & 31;
      sorted[off[nl] + atomicAdd(&cnt2[nl], 1)] = r;   // total <= 1024: in bounds
    }
  }
  __syncthreads();

  int w = t >> 6, lane = t & 63, o = lane & 31, rr = lane >> 5;
  float wA = Watt[2 * OUT_DIM];
  float bA = batt[0];
  const float kInvQ = 1.0f / 2047.0f;
#pragma unroll
  for (int k = 0; k < 4; ++k) {
    int nl = half * 16 + w * 4 + k;             // wave-uniform
    int n = bin * NODES_PER_BIN + nl;
    if (n >= N_NODES) break;
    int cn = hist[nl];
    int base = off[nl];
    float4 an = a_tab4[n];
    float adx = an.y, ady = an.w;               // a_d(n,b0), a_d(n,b1)
    float2 num = make_float2(0.f, 0.f), den = make_float2(0.f, 0.f);
    int i = 0;
    for (; i + 3 < cn; i += 4) {                // 2 records per half-wave iter
      unsigned int rA = sorted[base + i + rr];
      unsigned int rB = sorted[base + i + 2 + rr];
      int sA = rA >> 16, sB = rB >> 16;
      __half2 eA2 = ezh2[(size_t)sA * OUT_DIM + o];
      __half2 eB2 = ezh2[(size_t)sB * OUT_DIM + o];
      float4 aA = a_tab4[sA];
      float4 aB = a_tab4[sB];
      float wtA = fmaf((rA & 2047u) * kInvQ, wA, bA);
      float wtB = fmaf((rB & 2047u) * kInvQ, wA, bA);
      float l0A = aA.x + adx + wtA, l1A = aA.z + ady + wtA;
      float l0B = aB.x + adx + wtB, l1B = aB.z + ady + wtB;
      l0A = l0A > 0.f ? l0A : 0.01f * l0A;
      l1A = l1A > 0.f ? l1A : 0.01f * l1A;
      l0B = l0B > 0.f ? l0B : 0.01f * l0B;
      l1B = l1B > 0.f ? l1B : 0.01f * l1B;
      float2 eA = __half22float2(eA2);
      float2 eB = __half22float2(eB2);
      num.x = fmaf(eA.x, l0A, num.x); num.y = fmaf(eA.y, l1A, num.y);
      den.x += eA.x;                  den.y += eA.y;
      num.x = fmaf(eB.x, l0B, num.x); num.y = fmaf(eB.y, l1B, num.y);
      den.x += eB.x;                  den.y += eB.y;
    }
    for (; i < cn; i += 2) {                    // guarded tail
      int idx = i + rr;
      float m = (idx < cn) ? 1.f : 0.f;
      int idxc = (idx < cn) ? idx : cn - 1;
      unsigned int r = sorted[base + idxc];
      int s = r >> 16;
      __half2 e2 = ezh2[(size_t)s * OUT_DIM + o];
      float4 as4 = a_tab4[s];
      float wt = fmaf((r & 2047u) * kInvQ, wA, bA);
      float l0 = as4.x + adx + wt, l1 = as4.z + ady + wt;
      l0 = l0 > 0.f ? l0 : 0.01f * l0;
      l1 = l1 > 0.f ? l1 : 0.01f * l1;
      float2 e = __half22float2(e2);
      e.x *= m; e.y *= m;
      num.x = fmaf(e.x, l0, num.x); num.y = fmaf(e.y, l1, num.y);
      den.x += e.x;                 den.y += e.y;
    }
    num.x += __shfl_xor(num.x, 32, 64);
    num.y += __shfl_xor(num.y, 32, 64);
    den.x += __shfl_xor(den.x, 32, 64);
    den.y += __shfl_xor(den.y, 32, 64);
    if (rr == 0) {
      float v0 = (cn > 0) ? num.x / den.x : 0.f;
      float v1 = (cn > 0) ? num.y / den.y : 0.f;
      out[((size_t)0 * N_NODES + n) * OUT_DIM + o] = v0;
      out[((size_t)1 * N_NODES + n) * OUT_DIM + o] = v1;
    }
  }
}

extern "C" void kernel_launch(void* const* d_in, const int* in_sizes, int n_in,
                              void* d_out, int out_size, void* d_ws, size_t ws_size,
                              hipStream_t stream) {
  const float* h      = (const float*)d_in[0];
  const float* weight = (const float*)d_in[1];
  const int*   src    = (const int*)d_in[2];
  const int*   dst    = (const int*)d_in[3];
  const float* Wfc    = (const float*)d_in[4];
  const float* bfc    = (const float*)d_in[5];
  const float* Watt   = (const float*)d_in[6];
  const float* batt   = (const float*)d_in[7];
  float* out = (float*)d_out;

  // workspace (~13.7 MB)
  float4*       a_tab   = (float4*)d_ws;                                  // 800 KB
  unsigned int* payload = (unsigned int*)(a_tab + N_NODES);               // 6.4 MB
  __half2*      ezh2    = (__half2*)(payload + (size_t)NBINS * BIN_SLOTS);// 6.4 MB
  int*          cursor  = (int*)(ezh2 + (size_t)N_NODES * OUT_DIM);       // ~50 KB

  (void)hipMemsetAsync(cursor, 0, NCURS * sizeof(int), stream);
  fused_fc_scatter_kernel<<<SCATTER_BLOCKS + FC_BLOCKS, 256, 0, stream>>>(
      h, Wfc, bfc, Watt, src, dst, weight, ezh2, a_tab, cursor, payload);
  accum_kernel<<<NBINS * 2, 256, 0, stream>>>(ezh2, payload, cursor, a_tab,
                                              Watt, batt, out);
}

// Round 16
// 171.379 us; speedup vs baseline: 1.0325x; 1.0325x over previous
//
#include <hip/hip_runtime.h>
#include <hip/hip_fp16.h>

#define N_NODES 50000
#define N_EDGES 800000
#define IN_DIM  64
#define OUT_DIM 32
#define NODES_PER_BIN 32
#define NBINS   1563                 // ceil(50000/32)
#define NCLS    8
#define CLS_CAP 128                  // per (bin,class): mean 64, +8 sigma; chaining backstops
#define BIN_SLOTS (NCLS * CLS_CAP)   // 1024
#define NCURS   (NBINS * NCLS)       // 12504
#define SCATTER_BLOCKS (N_EDGES / 256)            // 3125 (1 edge/thread)
#define FC_NODES_PER_BLOCK 16
#define FC_BLOCKS (N_NODES / FC_NODES_PER_BLOCK)  // 3125

// physical XCD id (gfx950: HW_REG_XCC_ID = hwreg 20; learn_hip m09)
__device__ __forceinline__ int get_xcc_id() {
  return (int)(__builtin_amdgcn_s_getreg(63508) & 7u);  // 20 | (31<<11)
}

// Fused K1 (R12 config). R16 change: cursors TRANSPOSED to [cls][bin] so each
// 64B cursor line belongs to ONE XCD (old [bin][cls] layout put all 8 XCDs'
// classes on every line -> cross-XCD atomic line ping-pong at the head of
// every scatter chain).
// ezh2[n*32+o] = {exp(z[n,b0,o]), exp(z[n,b1,o])};  a_tab[n]=(as0,ad0,as1,ad1)
__global__ __launch_bounds__(256) void fused_fc_scatter_kernel(
    const float* __restrict__ h, const float* __restrict__ Wfc,
    const float* __restrict__ bfc, const float* __restrict__ Watt,
    const int* __restrict__ src, const int* __restrict__ dst,
    const float* __restrict__ weight,
    __half2* __restrict__ ezh2, float4* __restrict__ a_tab,
    int* __restrict__ cursor, unsigned int* __restrict__ payload) {
  __shared__ float Wl[IN_DIM * OUT_DIM];                    // 8 KB
  __shared__ float4 hs4[FC_NODES_PER_BLOCK * 2 * 16];       // 8 KB
  int t = threadIdx.x;

  if (blockIdx.x < SCATTER_BLOCKS) {
    int xcc = get_xcc_id();                  // wave-uniform
    int e = blockIdx.x * 256 + t;            // exact coverage
    int s = src[e], d = dst[e];
    float wv = weight[e];
    unsigned int rec = ((unsigned int)s << 16) | ((unsigned int)(d & 31) << 11) |
                       ((unsigned int)__float2int_rn(wv * 2047.0f) & 2047u);
    int bin = d >> 5;
    int c = xcc;
#pragma unroll
    for (int a = 0; a < NCLS; ++a) {
      int pos = atomicAdd(&cursor[c * NBINS + bin], 1);   // XCD-local line
      if (pos < CLS_CAP) {
        payload[(size_t)bin * BIN_SLOTS + c * CLS_CAP + pos] = rec;
        break;
      }
      c = (c + 1) & 7;                       // overflow chain: ~never taken
    }
    return;
  }

  // ---- fc role: 16 nodes per block ----
  int n0 = (blockIdx.x - SCATTER_BLOCKS) * FC_NODES_PER_BLOCK;
  for (int i = t; i < 512; i += 256)
    ((float4*)Wl)[i] = ((const float4*)Wfc)[i];
#pragma unroll
  for (int f = t; f < FC_NODES_PER_BLOCK * 2 * 16; f += 256) {
    int ns = f >> 5, sb = (f >> 4) & 1, i4 = f & 15;
    hs4[f] = ((const float4*)h)[((size_t)sb * N_NODES + (n0 + ns)) * 16 + i4];
  }
  __syncthreads();
  int w = t >> 6, lane = t & 63, o = lane & 31, b = lane >> 5;
  float wreg[IN_DIM];
#pragma unroll
  for (int i = 0; i < IN_DIM; ++i) wreg[i] = Wl[i * OUT_DIM + o];
  float bo = bfc[o];
  float wo1 = Watt[o], wo2 = Watt[OUT_DIM + o];
#pragma unroll
  for (int k = 0; k < 4; ++k) {
    int ns = w * 4 + k;
    int n = n0 + ns;
    float acc = bo;
#pragma unroll
    for (int i4 = 0; i4 < 16; ++i4) {
      float4 hv = hs4[(ns * 2 + b) * 16 + i4];   // wave-broadcast (2 addrs: free)
      acc = fmaf(hv.x, wreg[i4 * 4 + 0], acc);
      acc = fmaf(hv.y, wreg[i4 * 4 + 1], acc);
      acc = fmaf(hv.z, wreg[i4 * 4 + 2], acc);
      acc = fmaf(hv.w, wreg[i4 * 4 + 3], acc);
    }
    float ez = __expf(acc);
    float ezo = __shfl(ez, lane ^ 32, 64);       // partner batch's value
    if (b == 0) {
      __half2 hv2;
      hv2.x = __float2half(ez);
      hv2.y = __float2half(ezo);
      ezh2[(size_t)n * OUT_DIM + o] = hv2;
    }
    float ps = acc * wo1, pd = acc * wo2;
#pragma unroll
    for (int m = 16; m >= 1; m >>= 1) {
      ps += __shfl_xor(ps, m, 64);
      pd += __shfl_xor(pd, m, 64);
    }
    if (o == 0) ((float2*)(a_tab + n))[b] = make_float2(ps, pd);
  }
}

// K2 (R12's version): 4 blocks per bin; LDS counting sort (int atomics),
// each wave owns 2 nodes; half-wave (rr) record split; half2 ez gathers.
__global__ __launch_bounds__(256) void accum_kernel(
    const __half2* __restrict__ ezh2, const unsigned int* __restrict__ payload,
    const int* __restrict__ cursor, const float4* __restrict__ a_tab4,
    const float* __restrict__ Watt, const float* __restrict__ batt,
    float* __restrict__ out) {
  __shared__ unsigned int rec[BIN_SLOTS];     // 4 KB
  __shared__ unsigned int sorted[BIN_SLOTS];  // 4 KB
  __shared__ int c8[NCLS];
  __shared__ int hist[NODES_PER_BIN];
  __shared__ int off[NODES_PER_BIN];
  __shared__ int cnt2[NODES_PER_BIN];
  int t = threadIdx.x;
  int bin = blockIdx.x >> 2;
  int quad = blockIdx.x & 3;
  if (t < NCLS) {
    int c = cursor[t * NBINS + bin];          // transposed layout
    c8[t] = c > CLS_CAP ? CLS_CAP : (c < 0 ? 0 : c);
  }
  if (t < NODES_PER_BIN) { hist[t] = 0; cnt2[t] = 0; }
  __syncthreads();
  const unsigned int* seg = payload + (size_t)bin * BIN_SLOTS;
  for (int j = t; j < BIN_SLOTS; j += 256) {
    unsigned int r = seg[j];
    rec[j] = r;
    if ((j & (CLS_CAP - 1)) < c8[j >> 7]) atomicAdd(&hist[(r >> 11) & 31], 1);
  }
  __syncthreads();
  if (t < 64) {  // exclusive shuffle scan of 32 counts (wave 0)
    int v = (t < 32) ? hist[t] : 0;
    int orig = v;
#pragma unroll
    for (int d1 = 1; d1 < 32; d1 <<= 1) {
      int x = __shfl_up(v, d1, 64);
      if (t >= d1) v += x;
    }
    if (t < 32) off[t] = v - orig;
  }
  __syncthreads();
  for (int j = t; j < BIN_SLOTS; j += 256) {
    if ((j & (CLS_CAP - 1)) < c8[j >> 7]) {
      unsigned int r = rec[j];
      int nl = (r >> 11) & 31;
      sorted[off[nl] + atomicAdd(&cnt2[nl], 1)] = r;   // total <= 1024: in bounds
    }
  }
  __syncthreads();

  int w = t >> 6, lane = t & 63, o = lane & 31, rr = lane >> 5;
  float wA = Watt[2 * OUT_DIM];
  float bA = batt[0];
  const float kInvQ = 1.0f / 2047.0f;
#pragma unroll
  for (int k = 0; k < 2; ++k) {
    int nl = quad * 8 + w * 2 + k;              // wave-uniform
    int n = bin * NODES_PER_BIN + nl;
    if (n >= N_NODES) break;
    int cn = hist[nl];
    int base = off[nl];
    float4 an = a_tab4[n];
    float adx = an.y, ady = an.w;               // a_d(n,b0), a_d(n,b1)
    float2 num = make_float2(0.f, 0.f), den = make_float2(0.f, 0.f);
    int i = 0;
    for (; i + 3 < cn; i += 4) {                // 2 records per half-wave iter
      unsigned int rA = sorted[base + i + rr];
      unsigned int rB = sorted[base + i + 2 + rr];
      int sA = rA >> 16, sB = rB >> 16;
      __half2 eA2 = ezh2[(size_t)sA * OUT_DIM + o];
      __half2 eB2 = ezh2[(size_t)sB * OUT_DIM + o];
      float4 aA = a_tab4[sA];
      float4 aB = a_tab4[sB];
      float wtA = fmaf((rA & 2047u) * kInvQ, wA, bA);
      float wtB = fmaf((rB & 2047u) * kInvQ, wA, bA);
      float l0A = aA.x + adx + wtA, l1A = aA.z + ady + wtA;
      float l0B = aB.x + adx + wtB, l1B = aB.z + ady + wtB;
      l0A = l0A > 0.f ? l0A : 0.01f * l0A;
      l1A = l1A > 0.f ? l1A : 0.01f * l1A;
      l0B = l0B > 0.f ? l0B : 0.01f * l0B;
      l1B = l1B > 0.f ? l1B : 0.01f * l1B;
      float2 eA = __half22float2(eA2);
      float2 eB = __half22float2(eB2);
      num.x = fmaf(eA.x, l0A, num.x); num.y = fmaf(eA.y, l1A, num.y);
      den.x += eA.x;                  den.y += eA.y;
      num.x = fmaf(eB.x, l0B, num.x); num.y = fmaf(eB.y, l1B, num.y);
      den.x += eB.x;                  den.y += eB.y;
    }
    for (; i < cn; i += 2) {                    // guarded tail
      int idx = i + rr;
      float m = (idx < cn) ? 1.f : 0.f;
      int idxc = (idx < cn) ? idx : cn - 1;
      unsigned int r = sorted[base + idxc];
      int s = r >> 16;
      __half2 e2 = ezh2[(size_t)s * OUT_DIM + o];
      float4 as4 = a_tab4[s];
      float wt = fmaf((r & 2047u) * kInvQ, wA, bA);
      float l0 = as4.x + adx + wt, l1 = as4.z + ady + wt;
      l0 = l0 > 0.f ? l0 : 0.01f * l0;
      l1 = l1 > 0.f ? l1 : 0.01f * l1;
      float2 e = __half22float2(e2);
      e.x *= m; e.y *= m;
      num.x = fmaf(e.x, l0, num.x); num.y = fmaf(e.y, l1, num.y);
      den.x += e.x;                 den.y += e.y;
    }
    num.x += __shfl_xor(num.x, 32, 64);
    num.y += __shfl_xor(num.y, 32, 64);
    den.x += __shfl_xor(den.x, 32, 64);
    den.y += __shfl_xor(den.y, 32, 64);
    if (rr == 0) {
      float v0 = (cn > 0) ? num.x / den.x : 0.f;
      float v1 = (cn > 0) ? num.y / den.y : 0.f;
      out[((size_t)0 * N_NODES + n) * OUT_DIM + o] = v0;
      out[((size_t)1 * N_NODES + n) * OUT_DIM + o] = v1;
    }
  }
}

extern "C" void kernel_launch(void* const* d_in, const int* in_sizes, int n_in,
                              void* d_out, int out_size, void* d_ws, size_t ws_size,
                              hipStream_t stream) {
  const float* h      = (const float*)d_in[0];
  const float* weight = (const float*)d_in[1];
  const int*   src    = (const int*)d_in[2];
  const int*   dst    = (const int*)d_in[3];
  const float* Wfc    = (const float*)d_in[4];
  const float* bfc    = (const float*)d_in[5];
  const float* Watt   = (const float*)d_in[6];
  const float* batt   = (const float*)d_in[7];
  float* out = (float*)d_out;

  // workspace (~13.7 MB)
  float4*       a_tab   = (float4*)d_ws;                                  // 800 KB
  unsigned int* payload = (unsigned int*)(a_tab + N_NODES);               // 6.4 MB
  __half2*      ezh2    = (__half2*)(payload + (size_t)NBINS * BIN_SLOTS);// 6.4 MB
  int*          cursor  = (int*)(ezh2 + (size_t)N_NODES * OUT_DIM);       // ~50 KB

  (void)hipMemsetAsync(cursor, 0, NCURS * sizeof(int), stream);
  fused_fc_scatter_kernel<<<SCATTER_BLOCKS + FC_BLOCKS, 256, 0, stream>>>(
      h, Wfc, bfc, Watt, src, dst, weight, ezh2, a_tab, cursor, payload);
  accum_kernel<<<NBINS * 4, 256, 0, stream>>>(ezh2, payload, cursor, a_tab,
                                              Watt, batt, out);
}

// Round 17
// 168.629 us; speedup vs baseline: 1.0493x; 1.0163x over previous
//
#include <hip/hip_runtime.h>
#include <hip/hip_fp16.h>

#define N_NODES 50000
#define N_EDGES 800000
#define IN_DIM  64
#define OUT_DIM 32
#define NODES_PER_BIN 32
#define NBINS   1563                 // ceil(50000/32)
#define NCLS    8
#define CLS_CAP 128                  // per (bin,class): mean 64, +8 sigma; chaining backstops
#define BIN_SLOTS (NCLS * CLS_CAP)   // 1024
#define NCURS   (NBINS * NCLS)       // 12504
#define SCATTER_BLOCKS (N_EDGES / 256)            // 3125 (1 edge/thread)
#define FC_NODES_PER_BLOCK 16
#define FC_BLOCKS (N_NODES / FC_NODES_PER_BLOCK)  // 3125

// physical XCD id (gfx950: HW_REG_XCC_ID = hwreg 20; learn_hip m09)
__device__ __forceinline__ int get_xcc_id() {
  return (int)(__builtin_amdgcn_s_getreg(63508) & 7u);  // 20 | (31<<11)
}

// Fused K1 (R16 config): scatter blocks (1 edge/thread, XCC-id class +
// chaining, TRANSPOSED cursors [cls][bin] so each 64B cursor line is
// single-XCD) then fc blocks (16 nodes/block, W column register-cached).
// ezh2[n*32+o] = {exp(z[n,b0,o]), exp(z[n,b1,o])};  a_tab[n]=(as0,ad0,as1,ad1)
__global__ __launch_bounds__(256) void fused_fc_scatter_kernel(
    const float* __restrict__ h, const float* __restrict__ Wfc,
    const float* __restrict__ bfc, const float* __restrict__ Watt,
    const int* __restrict__ src, const int* __restrict__ dst,
    const float* __restrict__ weight,
    __half2* __restrict__ ezh2, float4* __restrict__ a_tab,
    int* __restrict__ cursor, unsigned int* __restrict__ payload) {
  __shared__ float Wl[IN_DIM * OUT_DIM];                    // 8 KB
  __shared__ float4 hs4[FC_NODES_PER_BLOCK * 2 * 16];       // 8 KB
  int t = threadIdx.x;

  if (blockIdx.x < SCATTER_BLOCKS) {
    int xcc = get_xcc_id();                  // wave-uniform
    int e = blockIdx.x * 256 + t;            // exact coverage
    int s = src[e], d = dst[e];
    float wv = weight[e];
    unsigned int rec = ((unsigned int)s << 16) | ((unsigned int)(d & 31) << 11) |
                       ((unsigned int)__float2int_rn(wv * 2047.0f) & 2047u);
    int bin = d >> 5;
    int c = xcc;
#pragma unroll
    for (int a = 0; a < NCLS; ++a) {
      int pos = atomicAdd(&cursor[c * NBINS + bin], 1);   // XCD-local line
      if (pos < CLS_CAP) {
        payload[(size_t)bin * BIN_SLOTS + c * CLS_CAP + pos] = rec;
        break;
      }
      c = (c + 1) & 7;                       // overflow chain: ~never taken
    }
    return;
  }

  // ---- fc role: 16 nodes per block ----
  int n0 = (blockIdx.x - SCATTER_BLOCKS) * FC_NODES_PER_BLOCK;
  for (int i = t; i < 512; i += 256)
    ((float4*)Wl)[i] = ((const float4*)Wfc)[i];
#pragma unroll
  for (int f = t; f < FC_NODES_PER_BLOCK * 2 * 16; f += 256) {
    int ns = f >> 5, sb = (f >> 4) & 1, i4 = f & 15;
    hs4[f] = ((const float4*)h)[((size_t)sb * N_NODES + (n0 + ns)) * 16 + i4];
  }
  __syncthreads();
  int w = t >> 6, lane = t & 63, o = lane & 31, b = lane >> 5;
  float wreg[IN_DIM];
#pragma unroll
  for (int i = 0; i < IN_DIM; ++i) wreg[i] = Wl[i * OUT_DIM + o];
  float bo = bfc[o];
  float wo1 = Watt[o], wo2 = Watt[OUT_DIM + o];
#pragma unroll
  for (int k = 0; k < 4; ++k) {
    int ns = w * 4 + k;
    int n = n0 + ns;
    float acc = bo;
#pragma unroll
    for (int i4 = 0; i4 < 16; ++i4) {
      float4 hv = hs4[(ns * 2 + b) * 16 + i4];   // wave-broadcast (2 addrs: free)
      acc = fmaf(hv.x, wreg[i4 * 4 + 0], acc);
      acc = fmaf(hv.y, wreg[i4 * 4 + 1], acc);
      acc = fmaf(hv.z, wreg[i4 * 4 + 2], acc);
      acc = fmaf(hv.w, wreg[i4 * 4 + 3], acc);
    }
    float ez = __expf(acc);
    float ezo = __shfl(ez, lane ^ 32, 64);       // partner batch's value
    if (b == 0) {
      __half2 hv2;
      hv2.x = __float2half(ez);
      hv2.y = __float2half(ezo);
      ezh2[(size_t)n * OUT_DIM + o] = hv2;
    }
    float ps = acc * wo1, pd = acc * wo2;
#pragma unroll
    for (int m = 16; m >= 1; m >>= 1) {
      ps += __shfl_xor(ps, m, 64);
      pd += __shfl_xor(pd, m, 64);
    }
    if (o == 0) ((float2*)(a_tab + n))[b] = make_float2(ps, pd);
  }
}

// K2 (R13's measured-best config): 2 blocks per bin; LDS counting sort (int
// atomics), each wave owns 4 nodes; half-wave (rr) record split; half2 ez
// gathers cover both batches per load.
__global__ __launch_bounds__(256) void accum_kernel(
    const __half2* __restrict__ ezh2, const unsigned int* __restrict__ payload,
    const int* __restrict__ cursor, const float4* __restrict__ a_tab4,
    const float* __restrict__ Watt, const float* __restrict__ batt,
    float* __restrict__ out) {
  __shared__ unsigned int rec[BIN_SLOTS];     // 4 KB
  __shared__ unsigned int sorted[BIN_SLOTS];  // 4 KB
  __shared__ int c8[NCLS];
  __shared__ int hist[NODES_PER_BIN];
  __shared__ int off[NODES_PER_BIN];
  __shared__ int cnt2[NODES_PER_BIN];
  int t = threadIdx.x;
  int bin = blockIdx.x >> 1;
  int half = blockIdx.x & 1;
  if (t < NCLS) {
    int c = cursor[t * NBINS + bin];          // transposed layout
    c8[t] = c > CLS_CAP ? CLS_CAP : (c < 0 ? 0 : c);
  }
  if (t < NODES_PER_BIN) { hist[t] = 0; cnt2[t] = 0; }
  __syncthreads();
  const unsigned int* seg = payload + (size_t)bin * BIN_SLOTS;
  for (int j = t; j < BIN_SLOTS; j += 256) {
    unsigned int r = seg[j];
    rec[j] = r;
    if ((j & (CLS_CAP - 1)) < c8[j >> 7]) atomicAdd(&hist[(r >> 11) & 31], 1);
  }
  __syncthreads();
  if (t < 64) {  // exclusive shuffle scan of 32 counts (wave 0)
    int v = (t < 32) ? hist[t] : 0;
    int orig = v;
#pragma unroll
    for (int d1 = 1; d1 < 32; d1 <<= 1) {
      int x = __shfl_up(v, d1, 64);
      if (t >= d1) v += x;
    }
    if (t < 32) off[t] = v - orig;
  }
  __syncthreads();
  for (int j = t; j < BIN_SLOTS; j += 256) {
    if ((j & (CLS_CAP - 1)) < c8[j >> 7]) {
      unsigned int r = rec[j];
      int nl = (r >> 11) & 31;
      sorted[off[nl] + atomicAdd(&cnt2[nl], 1)] = r;   // total <= 1024: in bounds
    }
  }
  __syncthreads();

  int w = t >> 6, lane = t & 63, o = lane & 31, rr = lane >> 5;
  float wA = Watt[2 * OUT_DIM];
  float bA = batt[0];
  const float kInvQ = 1.0f / 2047.0f;
#pragma unroll
  for (int k = 0; k < 4; ++k) {
    int nl = half * 16 + w * 4 + k;             // wave-uniform
    int n = bin * NODES_PER_BIN + nl;
    if (n >= N_NODES) break;
    int cn = hist[nl];
    int base = off[nl];
    float4 an = a_tab4[n];
    float adx = an.y, ady = an.w;               // a_d(n,b0), a_d(n,b1)
    float2 num = make_float2(0.f, 0.f), den = make_float2(0.f, 0.f);
    int i = 0;
    for (; i + 3 < cn; i += 4) {                // 2 records per half-wave iter
      unsigned int rA = sorted[base + i + rr];
      unsigned int rB = sorted[base + i + 2 + rr];
      int sA = rA >> 16, sB = rB >> 16;
      __half2 eA2 = ezh2[(size_t)sA * OUT_DIM + o];
      __half2 eB2 = ezh2[(size_t)sB * OUT_DIM + o];
      float4 aA = a_tab4[sA];
      float4 aB = a_tab4[sB];
      float wtA = fmaf((rA & 2047u) * kInvQ, wA, bA);
      float wtB = fmaf((rB & 2047u) * kInvQ, wA, bA);
      float l0A = aA.x + adx + wtA, l1A = aA.z + ady + wtA;
      float l0B = aB.x + adx + wtB, l1B = aB.z + ady + wtB;
      l0A = l0A > 0.f ? l0A : 0.01f * l0A;
      l1A = l1A > 0.f ? l1A : 0.01f * l1A;
      l0B = l0B > 0.f ? l0B : 0.01f * l0B;
      l1B = l1B > 0.f ? l1B : 0.01f * l1B;
      float2 eA = __half22float2(eA2);
      float2 eB = __half22float2(eB2);
      num.x = fmaf(eA.x, l0A, num.x); num.y = fmaf(eA.y, l1A, num.y);
      den.x += eA.x;                  den.y += eA.y;
      num.x = fmaf(eB.x, l0B, num.x); num.y = fmaf(eB.y, l1B, num.y);
      den.x += eB.x;                  den.y += eB.y;
    }
    for (; i < cn; i += 2) {                    // guarded tail
      int idx = i + rr;
      float m = (idx < cn) ? 1.f : 0.f;
      int idxc = (idx < cn) ? idx : cn - 1;
      unsigned int r = sorted[base + idxc];
      int s = r >> 16;
      __half2 e2 = ezh2[(size_t)s * OUT_DIM + o];
      float4 as4 = a_tab4[s];
      float wt = fmaf((r & 2047u) * kInvQ, wA, bA);
      float l0 = as4.x + adx + wt, l1 = as4.z + ady + wt;
      l0 = l0 > 0.f ? l0 : 0.01f * l0;
      l1 = l1 > 0.f ? l1 : 0.01f * l1;
      float2 e = __half22float2(e2);
      e.x *= m; e.y *= m;
      num.x = fmaf(e.x, l0, num.x); num.y = fmaf(e.y, l1, num.y);
      den.x += e.x;                 den.y += e.y;
    }
    num.x += __shfl_xor(num.x, 32, 64);
    num.y += __shfl_xor(num.y, 32, 64);
    den.x += __shfl_xor(den.x, 32, 64);
    den.y += __shfl_xor(den.y, 32, 64);
    if (rr == 0) {
      float v0 = (cn > 0) ? num.x / den.x : 0.f;
      float v1 = (cn > 0) ? num.y / den.y : 0.f;
      out[((size_t)0 * N_NODES + n) * OUT_DIM + o] = v0;
      out[((size_t)1 * N_NODES + n) * OUT_DIM + o] = v1;
    }
  }
}

extern "C" void kernel_launch(void* const* d_in, const int* in_sizes, int n_in,
                              void* d_out, int out_size, void* d_ws, size_t ws_size,
                              hipStream_t stream) {
  const float* h      = (const float*)d_in[0];
  const float* weight = (const float*)d_in[1];
  const int*   src    = (const int*)d_in[2];
  const int*   dst    = (const int*)d_in[3];
  const float* Wfc    = (const float*)d_in[4];
  const float* bfc    = (const float*)d_in[5];
  const float* Watt   = (const float*)d_in[6];
  const float* batt   = (const float*)d_in[7];
  float* out = (float*)d_out;

  // workspace (~13.7 MB)
  float4*       a_tab   = (float4*)d_ws;                                  // 800 KB
  unsigned int* payload = (unsigned int*)(a_tab + N_NODES);               // 6.4 MB
  __half2*      ezh2    = (__half2*)(payload + (size_t)NBINS * BIN_SLOTS);// 6.4 MB
  int*          cursor  = (int*)(ezh2 + (size_t)N_NODES * OUT_DIM);       // ~50 KB

  (void)hipMemsetAsync(cursor, 0, NCURS * sizeof(int), stream);
  fused_fc_scatter_kernel<<<SCATTER_BLOCKS + FC_BLOCKS, 256, 0, stream>>>(
      h, Wfc, bfc, Watt, src, dst, weight, ezh2, a_tab, cursor, payload);
  accum_kernel<<<NBINS * 2, 256, 0, stream>>>(ezh2, payload, cursor, a_tab,
                                              Watt, batt, out);
}